// Round 10
// baseline (407.485 us; speedup 1.0000x reference)
//
#include <hip/hip_runtime.h>
#include <cstdint>
#include <cstddef>

// CRF forward NLL: B=512 chains, S=1024 steps, T=64 states.
// One wave per batch element. Exp-domain recurrence, quarter-split matvec.
//   lane l = (g = l>>2, c = l&3) owns state j = 4g+c = l.
// Round-9 postmortem: fixing spills (VGPR 60->132) changed nothing ->
// the ~400 cy/step stall is the LDS write->read round trip of A, not
// scratch. This version has NO LDS on the serial chain: each step pulls
// its A-quarter A[16c..16c+15] straight from the owning lanes' registers
// via 16x ds_bpermute_b32 (one LDS-pipe crossing, no write, no round trip).
//   P[r] = sum_{i in quarter} A[i]*E[i][4g+r]  (32 pk-FMAs, E in VGPRs),
//   quad DPP butterfly (xor1,xor2) + select -> s_l,
//   A_new = s_l * exp(emit_l) * 2^-pend (pend = prev lane0 exponent, off-chain),
//   Mk accumulates applied exponents exactly. Same op order as r7 -> bit-identical.

#define S_ 1024
#define T_ 64

typedef float f32x2 __attribute__((ext_vector_type(2)));
typedef float f32x4 __attribute__((ext_vector_type(4)));

__device__ __forceinline__ float rl_f(float v, int lane) {
  return __int_as_float(__builtin_amdgcn_readlane(__float_as_int(v), lane));
}

template <int CTRL>
__device__ __forceinline__ float dppq(float v) {
  // quad_perm DPP: CTRL=0xB1 -> lane^1, CTRL=0x4E -> lane^2 (within quads)
  return __int_as_float(__builtin_amdgcn_update_dpp(
      0, __float_as_int(v), CTRL, 0xF, 0xF, true));
}

// one pk-FMA group: A-pair (AVX,AVY) times E columns for this group's 4 states
#define FMA4(AVX, AVY, P) { \
  f32x2 av_; av_.x = (AVX); av_.y = (AVY); \
  P0_ += av_ * er2[0][P]; P1_ += av_ * er2[1][P]; \
  P2_ += av_ * er2[2][P]; P3_ += av_ * er2[3][P]; }

#define BPF(K) __int_as_float(__builtin_amdgcn_ds_bpermute(bidx##K, aw_))

// one scan step (t>=1). No LDS buffers: A pulled from lanes' registers.
#define STEPF(TMT, ECU, EEU) { \
  const int tmt_ = (TMT); \
  const int tag_ = tmt_ & 255; \
  const int mk_  = (tmt_ >> 8) & 1; \
  const float ce_ = (EEU) * scale_pend; \
  const int aw_ = __float_as_int(Aprev); \
  const float b0_  = BPF(0),  b1_  = BPF(1),  b2_  = BPF(2),  b3_  = BPF(3); \
  const float b4_  = BPF(4),  b5_  = BPF(5),  b6_  = BPF(6),  b7_  = BPF(7); \
  const float b8_  = BPF(8),  b9_  = BPF(9),  b10_ = BPF(10), b11_ = BPF(11); \
  const float b12_ = BPF(12), b13_ = BPF(13), b14_ = BPF(14), b15_ = BPF(15); \
  f32x2 P0_ = {0.f, 0.f}, P1_ = {0.f, 0.f}, P2_ = {0.f, 0.f}, P3_ = {0.f, 0.f}; \
  FMA4(b0_,  b1_,  0); FMA4(b2_,  b3_,  1); \
  FMA4(b4_,  b5_,  2); FMA4(b6_,  b7_,  3); \
  FMA4(b8_,  b9_,  4); FMA4(b10_, b11_, 5); \
  FMA4(b12_, b13_, 6); FMA4(b14_, b15_, 7); \
  float p0_ = P0_.x + P0_.y, p1_ = P1_.x + P1_.y; \
  float p2_ = P2_.x + P2_.y, p3_ = P3_.x + P3_.y; \
  float qq0_ = p0_ + dppq<0xB1>(p0_); \
  float qq1_ = p1_ + dppq<0xB1>(p1_); \
  float qq2_ = p2_ + dppq<0xB1>(p2_); \
  float qq3_ = p3_ + dppq<0xB1>(p3_); \
  float r0_ = qq0_ + dppq<0x4E>(qq0_); \
  float r1_ = qq1_ + dppq<0x4E>(qq1_); \
  float r2_ = qq2_ + dppq<0x4E>(qq2_); \
  float r3_ = qq3_ + dppq<0x4E>(qq3_); \
  float s01_ = (c & 1) ? r1_ : r0_; \
  float s23_ = (c & 1) ? r3_ : r2_; \
  float s_ = (c & 2) ? s23_ : s01_; \
  float An_ = s_ * ce_; \
  Aprev = mk_ ? An_ : Aprev; \
  Mk += mk_ ? pend : 0; \
  int wb_ = __builtin_amdgcn_readfirstlane(__float_as_int(Aprev)); \
  pend = (int)(((unsigned)wb_ >> 23) & 255) - 127; \
  scale_pend = __int_as_float((127 - pend) << 23); \
  gold += mk_ ? rl_f((ECU), tag_) : 0.0f; \
}

#define RL(V, U) __builtin_amdgcn_readlane((V), (U))

__launch_bounds__(64)
__attribute__((amdgpu_waves_per_eu(1, 1)))
__global__ void crf_scan(const float* __restrict__ feats,
                         const int* __restrict__ tags,
                         const int* __restrict__ mask,
                         const float* __restrict__ trans,
                         float* __restrict__ out) {
  const int b = blockIdx.x;
  const int lane = threadIdx.x;
  const int g = lane >> 2;   // group 0..15 (owns states 4g..4g+3)
  const int c = lane & 3;    // quad pos == A-quarter index

  __shared__ int tmeta[S_];

  const float LOG2E = 1.4426950408889634f;

  // loop-invariant bpermute byte-indices: source lanes 16c+0..15
  const int bidx0  = (16 * c + 0)  << 2, bidx1  = (16 * c + 1)  << 2;
  const int bidx2  = (16 * c + 2)  << 2, bidx3  = (16 * c + 3)  << 2;
  const int bidx4  = (16 * c + 4)  << 2, bidx5  = (16 * c + 5)  << 2;
  const int bidx6  = (16 * c + 6)  << 2, bidx7  = (16 * c + 7)  << 2;
  const int bidx8  = (16 * c + 8)  << 2, bidx9  = (16 * c + 9)  << 2;
  const int bidx10 = (16 * c + 10) << 2, bidx11 = (16 * c + 11) << 2;
  const int bidx12 = (16 * c + 12) << 2, bidx13 = (16 * c + 13) << 2;
  const int bidx14 = (16 * c + 14) << 2, bidx15 = (16 * c + 15) << 2;

  // ---- stage tags+mask into LDS as (tag | mask<<8), coalesced ----
  const int* tagb = tags + (size_t)b * S_;
  const int* mb = mask + (size_t)b * S_;
  #pragma unroll
  for (int t0 = 0; t0 < S_; t0 += 64) {
    int t = t0 + lane;
    tmeta[t] = (tagb[t] & 63) | (mb[t] != 0 ? 256 : 0);
  }

  // ---- E fragments: er2[r][p] = {E[16c+2p][4g+r], E[16c+2p+1][4g+r]} ----
  f32x2 er2[4][8];
  #pragma unroll
  for (int r = 0; r < 4; ++r) {
    #pragma unroll
    for (int p = 0; p < 8; ++p) {
      int i0 = 16 * c + 2 * p;
      int j = 4 * g + r;
      f32x2 e;
      e.x = exp2f(trans[(size_t)i0 * T_ + j] * LOG2E);
      e.y = exp2f(trans[(size_t)(i0 + 1) * T_ + j] * LOG2E);
      er2[r][p] = e;
    }
  }

  // ---- gold: precompute transition term lane-parallel (t = 1..1023) ----
  float gtr = 0.0f;
  #pragma unroll
  for (int u = 0; u < 16; ++u) {
    int t = lane * 16 + u + 1;
    if (t < S_) {
      int m1 = tmeta[t];
      if (m1 & 256) {
        int m0 = tmeta[t - 1];
        gtr += trans[(m0 & 255) * T_ + (m1 & 255)];
      }
    }
  }

  // ---- t = 0 init ----
  const float* fb = feats + (size_t)b * S_ * T_ + lane;
  float e0i = fb[0];                // emit[b,0,lane] == alpha0[lane]
  float Aprev = exp2f(e0i * LOG2E);
  int Mk = 0;                       // applied exponent sum (exact, uniform)
  int wb0 = __builtin_amdgcn_readfirstlane(__float_as_int(Aprev));
  int pend = (int)(((unsigned)wb0 >> 23) & 255) - 127;   // lane0 exponent
  float scale_pend = __int_as_float((127 - pend) << 23); // 2^-pend

  int tm0 = __builtin_amdgcn_readfirstlane(tmeta[0]);
  float gold = (tm0 & 256) ? rl_f(e0i, tm0 & 255) : 0.0f;

  // ---- prefetch first chunk of emits (t = 1..8), named scalars only ----
  float epf0 = fb[(size_t)1 * T_], epf1 = fb[(size_t)2 * T_];
  float epf2 = fb[(size_t)3 * T_], epf3 = fb[(size_t)4 * T_];
  float epf4 = fb[(size_t)5 * T_], epf5 = fb[(size_t)6 * T_];
  float epf6 = fb[(size_t)7 * T_], epf7 = fb[(size_t)8 * T_];

  // ---- main scan: 127 chunks of 8 steps (t = 1..1016) ----
  for (int cc = 0; cc < 127; ++cc) {
    const int tbase = 1 + cc * 8;

    float ec0 = epf0, ec1 = epf1, ec2 = epf2, ec3 = epf3;
    float ec4 = epf4, ec5 = epf5, ec6 = epf6, ec7 = epf7;
    float ex0 = exp2f(ec0 * LOG2E), ex1 = exp2f(ec1 * LOG2E);
    float ex2 = exp2f(ec2 * LOG2E), ex3 = exp2f(ec3 * LOG2E);
    float ex4 = exp2f(ec4 * LOG2E), ex5 = exp2f(ec5 * LOG2E);
    float ex6 = exp2f(ec6 * LOG2E), ex7 = exp2f(ec7 * LOG2E);

    // chunk metadata: lanes 0..7 hold tmeta[tbase+0..7]
    int tmv = tmeta[tbase + (lane & 7)];

    // prefetch next chunk (tbase+8 .. tbase+15; only +15 can be OOB)
    {
      const float* fpn = fb + (size_t)(tbase + 8) * T_;
      epf0 = fpn[0 * T_]; epf1 = fpn[1 * T_];
      epf2 = fpn[2 * T_]; epf3 = fpn[3 * T_];
      epf4 = fpn[4 * T_]; epf5 = fpn[5 * T_];
      epf6 = fpn[6 * T_];
      int t7 = tbase + 15;
      epf7 = fb[(size_t)(t7 < S_ ? t7 : S_ - 1) * T_];
    }

    STEPF(RL(tmv, 0), ec0, ex0);
    STEPF(RL(tmv, 1), ec1, ex1);
    STEPF(RL(tmv, 2), ec2, ex2);
    STEPF(RL(tmv, 3), ec3, ex3);
    STEPF(RL(tmv, 4), ec4, ex4);
    STEPF(RL(tmv, 5), ec5, ex5);
    STEPF(RL(tmv, 6), ec6, ex6);
    STEPF(RL(tmv, 7), ec7, ex7);
  }

  // ---- tail: t = 1017..1023 (7 steps) ----
  {
    int tt = 1017 + (lane & 7);
    if (tt > 1023) tt = 1023;
    int tmv = tmeta[tt];
    float ex0 = exp2f(epf0 * LOG2E), ex1 = exp2f(epf1 * LOG2E);
    float ex2 = exp2f(epf2 * LOG2E), ex3 = exp2f(epf3 * LOG2E);
    float ex4 = exp2f(epf4 * LOG2E), ex5 = exp2f(epf5 * LOG2E);
    float ex6 = exp2f(epf6 * LOG2E);

    STEPF(RL(tmv, 0), epf0, ex0);
    STEPF(RL(tmv, 1), epf1, ex1);
    STEPF(RL(tmv, 2), epf2, ex2);
    STEPF(RL(tmv, 3), epf3, ex3);
    STEPF(RL(tmv, 4), epf4, ex4);
    STEPF(RL(tmv, 5), epf5, ex5);
    STEPF(RL(tmv, 6), epf6, ex6);
  }

  // ---- norm = Mk*ln2 + ln(sum_j A[j]); out = norm - gold ----
  float ssum = Aprev;
  float gsum = gtr;
  #pragma unroll
  for (int k = 32; k >= 1; k >>= 1) {
    ssum += __shfl_xor(ssum, k, 64);
    gsum += __shfl_xor(gsum, k, 64);
  }
  double norm = ((double)Mk + (double)log2f(ssum)) * 0.6931471805599453;
  double goldall = (double)gold + (double)gsum;
  if (lane == 0) out[b] = (float)(norm - goldall);
}

extern "C" void kernel_launch(void* const* d_in, const int* in_sizes, int n_in,
                              void* d_out, int out_size, void* d_ws, size_t ws_size,
                              hipStream_t stream) {
  const float* feats = (const float*)d_in[0];
  const int* tags = (const int*)d_in[1];
  const int* mask = (const int*)d_in[2];
  const float* trans = (const float*)d_in[3];
  float* out = (float*)d_out;

  int Bn = in_sizes[0] / (S_ * T_);  // 512
  hipLaunchKernelGGL(crf_scan, dim3(Bn), dim3(64), 0, stream,
                     feats, tags, mask, trans, out);
}

// Round 11
// 391.621 us; speedup vs baseline: 1.0405x; 1.0405x over previous
//
#include <hip/hip_runtime.h>
#include <cstdint>
#include <cstddef>

// CRF forward NLL: B=512 chains, S=1024 steps, T=64 states.
// One wave per batch element, lane l owns state l. Row-gather scheme:
//   lane l: row r = l>>4 (16-lane DPP row), pos p = l&15.
//   chunk(r) = states {16r..16r+15} (owned by row r's lanes).
// Per step:
//   1. Row all-gather of A via 15x DPP row_ror (pure VALU, no LDS!) ->
//      a_k = A[idx_k], idx_k self-aligned at setup (same DPP on lane index).
//   2. P[m] = sum_k a_k * E[idx_k][16m+p]  (32 pk-FMAs, E in VGPRs):
//      partial over chunk(r) for state 16m+p.
//   3. Combine across column {p,p+16,p+32,p+48}: pre-select P[r^j], then
//      s = P[r] + swz16(P[r^1]) + bperm32(P[r^2]) + bperm48(P[r^3]) --
//      3 INDEPENDENT xor-pattern pulls (conflict-free), ONE latency block.
//   4. A_new = s * exp(emit_l) * 2^-pend (pend = prev lane0 exp, off-chain).
// r9 postmortem: ds_write->ds_read round trip was ~240cy of the 537cy step.
// r10 postmortem: 16x bpermute gather = 17M bank conflicts (no broadcast in
// the crossbar) -> regression. This version has ZERO LDS ops on the chain
// except the single 3-pull combine block.

#define S_ 1024
#define T_ 64

typedef float f32x2 __attribute__((ext_vector_type(2)));

__device__ __forceinline__ float rl_f(float v, int lane) {
  return __int_as_float(__builtin_amdgcn_readlane(__float_as_int(v), lane));
}

// DPP row_ror:K on Aprev (float), all rows/banks, bound_ctrl on
#define RORF(K) __int_as_float(__builtin_amdgcn_update_dpp( \
    0, __float_as_int(Aprev), 0x120 + (K), 0xF, 0xF, true))

// LDS-pipe pulls: swizzle xor-16 (BitMode 0x401F), bpermute by byte index
#define SWZ16(X) __int_as_float(__builtin_amdgcn_ds_swizzle(__float_as_int(X), 0x401F))
#define BPERMF(IDX, X) __int_as_float(__builtin_amdgcn_ds_bpermute((IDX), __float_as_int(X)))

// 4 pk-FMAs: one A-pair times the E-pairs of this lane's 4 partial states
#define FMA4R(AV, K2) { \
  P0_ += (AV) * er2[0][K2]; P1_ += (AV) * er2[1][K2]; \
  P2_ += (AV) * er2[2][K2]; P3_ += (AV) * er2[3][K2]; }

// one scan step (t>=1)
#define STEPF(TMT, ECU, EEU) { \
  const int tmt_ = (TMT); \
  const int tag_ = tmt_ & 255; \
  const int mk_  = (tmt_ >> 8) & 1; \
  const float ce_ = (EEU) * scale_pend; \
  f32x2 av0_, av1_, av2_, av3_, av4_, av5_, av6_, av7_; \
  av0_.x = Aprev;    av0_.y = RORF(1); \
  av1_.x = RORF(2);  av1_.y = RORF(3); \
  av2_.x = RORF(4);  av2_.y = RORF(5); \
  av3_.x = RORF(6);  av3_.y = RORF(7); \
  av4_.x = RORF(8);  av4_.y = RORF(9); \
  av5_.x = RORF(10); av5_.y = RORF(11); \
  av6_.x = RORF(12); av6_.y = RORF(13); \
  av7_.x = RORF(14); av7_.y = RORF(15); \
  f32x2 P0_ = {0.f, 0.f}, P1_ = {0.f, 0.f}, P2_ = {0.f, 0.f}, P3_ = {0.f, 0.f}; \
  FMA4R(av0_, 0); FMA4R(av1_, 1); FMA4R(av2_, 2); FMA4R(av3_, 3); \
  FMA4R(av4_, 4); FMA4R(av5_, 5); FMA4R(av6_, 6); FMA4R(av7_, 7); \
  float p0_ = P0_.x + P0_.y, p1_ = P1_.x + P1_.y; \
  float p2_ = P2_.x + P2_.y, p3_ = P3_.x + P3_.y; \
  float e0_ = is16 ? (is32 ? p3_ : p1_) : (is32 ? p2_ : p0_);  /* P[r]   */ \
  float e1_ = is16 ? (is32 ? p2_ : p0_) : (is32 ? p3_ : p1_);  /* P[r^1] */ \
  float e2_ = is16 ? (is32 ? p1_ : p3_) : (is32 ? p0_ : p2_);  /* P[r^2] */ \
  float e3_ = is16 ? (is32 ? p0_ : p2_) : (is32 ? p1_ : p3_);  /* P[r^3] */ \
  float n1_ = SWZ16(e1_); \
  float n2_ = BPERMF(bp32i, e2_); \
  float n3_ = BPERMF(bp48i, e3_); \
  float s_ = (e0_ + n1_) + (n2_ + n3_); \
  float An_ = s_ * ce_; \
  Aprev = mk_ ? An_ : Aprev; \
  Mk += mk_ ? pend : 0; \
  int wb_ = __builtin_amdgcn_readfirstlane(__float_as_int(Aprev)); \
  pend = (int)(((unsigned)wb_ >> 23) & 255) - 127; \
  scale_pend = __int_as_float((127 - pend) << 23); \
  gold += mk_ ? rl_f((ECU), tag_) : 0.0f; \
}

#define RL(V, U) __builtin_amdgcn_readlane((V), (U))

__launch_bounds__(64)
__attribute__((amdgpu_waves_per_eu(1, 1)))
__global__ void crf_scan(const float* __restrict__ feats,
                         const int* __restrict__ tags,
                         const int* __restrict__ mask,
                         const float* __restrict__ trans,
                         float* __restrict__ out) {
  const int b = blockIdx.x;
  const int lane = threadIdx.x;
  const int p = lane & 15;                 // pos within DPP row
  const bool is16 = (lane & 16) != 0;      // row bit0
  const bool is32 = (lane & 32) != 0;      // row bit1
  const int bp32i = (lane ^ 32) << 2;      // bpermute byte indices
  const int bp48i = (lane ^ 48) << 2;

  __shared__ int tmeta[S_];

  const float LOG2E = 1.4426950408889634f;

  // ---- stage tags+mask into LDS as (tag | mask<<8), coalesced ----
  const int* tagb = tags + (size_t)b * S_;
  const int* mb = mask + (size_t)b * S_;
  #pragma unroll
  for (int t0 = 0; t0 < S_; t0 += 64) {
    int t = t0 + lane;
    tmeta[t] = (tagb[t] & 63) | (mb[t] != 0 ? 256 : 0);
  }

  // ---- self-aligned gather indices: apply the SAME DPP to the lane id.
  // idx_k[l] = source lane of row_ror:k = state whose A lands in a_k.
  const int idx0 = lane;
  const int idx1  = __builtin_amdgcn_update_dpp(0, lane, 0x121, 0xF, 0xF, true);
  const int idx2  = __builtin_amdgcn_update_dpp(0, lane, 0x122, 0xF, 0xF, true);
  const int idx3  = __builtin_amdgcn_update_dpp(0, lane, 0x123, 0xF, 0xF, true);
  const int idx4  = __builtin_amdgcn_update_dpp(0, lane, 0x124, 0xF, 0xF, true);
  const int idx5  = __builtin_amdgcn_update_dpp(0, lane, 0x125, 0xF, 0xF, true);
  const int idx6  = __builtin_amdgcn_update_dpp(0, lane, 0x126, 0xF, 0xF, true);
  const int idx7  = __builtin_amdgcn_update_dpp(0, lane, 0x127, 0xF, 0xF, true);
  const int idx8  = __builtin_amdgcn_update_dpp(0, lane, 0x128, 0xF, 0xF, true);
  const int idx9  = __builtin_amdgcn_update_dpp(0, lane, 0x129, 0xF, 0xF, true);
  const int idx10 = __builtin_amdgcn_update_dpp(0, lane, 0x12A, 0xF, 0xF, true);
  const int idx11 = __builtin_amdgcn_update_dpp(0, lane, 0x12B, 0xF, 0xF, true);
  const int idx12 = __builtin_amdgcn_update_dpp(0, lane, 0x12C, 0xF, 0xF, true);
  const int idx13 = __builtin_amdgcn_update_dpp(0, lane, 0x12D, 0xF, 0xF, true);
  const int idx14 = __builtin_amdgcn_update_dpp(0, lane, 0x12E, 0xF, 0xF, true);
  const int idx15 = __builtin_amdgcn_update_dpp(0, lane, 0x12F, 0xF, 0xF, true);
  const int idxs[16] = {idx0, idx1, idx2, idx3, idx4, idx5, idx6, idx7,
                        idx8, idx9, idx10, idx11, idx12, idx13, idx14, idx15};

  // ---- E fragments: er2[m][k2] = {E[idx_{2k2}][16m+p], E[idx_{2k2+1}][16m+p]}
  f32x2 er2[4][8];
  #pragma unroll
  for (int m = 0; m < 4; ++m) {
    #pragma unroll
    for (int k2 = 0; k2 < 8; ++k2) {
      f32x2 e;
      e.x = exp2f(trans[(size_t)idxs[2 * k2]     * T_ + 16 * m + p] * LOG2E);
      e.y = exp2f(trans[(size_t)idxs[2 * k2 + 1] * T_ + 16 * m + p] * LOG2E);
      er2[m][k2] = e;
    }
  }

  // ---- gold: precompute transition term lane-parallel (t = 1..1023) ----
  float gtr = 0.0f;
  #pragma unroll
  for (int u = 0; u < 16; ++u) {
    int t = lane * 16 + u + 1;
    if (t < S_) {
      int m1 = tmeta[t];
      if (m1 & 256) {
        int m0 = tmeta[t - 1];
        gtr += trans[(m0 & 255) * T_ + (m1 & 255)];
      }
    }
  }

  // ---- t = 0 init ----
  const float* fb = feats + (size_t)b * S_ * T_ + lane;
  float e0i = fb[0];                // emit[b,0,lane] == alpha0[state lane]
  float Aprev = exp2f(e0i * LOG2E);
  int Mk = 0;                       // applied exponent sum (exact, uniform)
  int wb0 = __builtin_amdgcn_readfirstlane(__float_as_int(Aprev));
  int pend = (int)(((unsigned)wb0 >> 23) & 255) - 127;   // lane0 exponent
  float scale_pend = __int_as_float((127 - pend) << 23); // 2^-pend

  int tm0 = __builtin_amdgcn_readfirstlane(tmeta[0]);
  float gold = (tm0 & 256) ? rl_f(e0i, tm0 & 255) : 0.0f;

  // ---- prefetch first chunk of emits (t = 1..8), named scalars only ----
  float epf0 = fb[(size_t)1 * T_], epf1 = fb[(size_t)2 * T_];
  float epf2 = fb[(size_t)3 * T_], epf3 = fb[(size_t)4 * T_];
  float epf4 = fb[(size_t)5 * T_], epf5 = fb[(size_t)6 * T_];
  float epf6 = fb[(size_t)7 * T_], epf7 = fb[(size_t)8 * T_];

  // ---- main scan: 127 chunks of 8 steps (t = 1..1016) ----
  for (int cc = 0; cc < 127; ++cc) {
    const int tbase = 1 + cc * 8;

    float ec0 = epf0, ec1 = epf1, ec2 = epf2, ec3 = epf3;
    float ec4 = epf4, ec5 = epf5, ec6 = epf6, ec7 = epf7;
    float ex0 = exp2f(ec0 * LOG2E), ex1 = exp2f(ec1 * LOG2E);
    float ex2 = exp2f(ec2 * LOG2E), ex3 = exp2f(ec3 * LOG2E);
    float ex4 = exp2f(ec4 * LOG2E), ex5 = exp2f(ec5 * LOG2E);
    float ex6 = exp2f(ec6 * LOG2E), ex7 = exp2f(ec7 * LOG2E);

    // chunk metadata: lanes 0..7 hold tmeta[tbase+0..7]
    int tmv = tmeta[tbase + (lane & 7)];

    // prefetch next chunk (tbase+8 .. tbase+15; only +15 can be OOB)
    {
      const float* fpn = fb + (size_t)(tbase + 8) * T_;
      epf0 = fpn[0 * T_]; epf1 = fpn[1 * T_];
      epf2 = fpn[2 * T_]; epf3 = fpn[3 * T_];
      epf4 = fpn[4 * T_]; epf5 = fpn[5 * T_];
      epf6 = fpn[6 * T_];
      int t7 = tbase + 15;
      epf7 = fb[(size_t)(t7 < S_ ? t7 : S_ - 1) * T_];
    }

    STEPF(RL(tmv, 0), ec0, ex0);
    STEPF(RL(tmv, 1), ec1, ex1);
    STEPF(RL(tmv, 2), ec2, ex2);
    STEPF(RL(tmv, 3), ec3, ex3);
    STEPF(RL(tmv, 4), ec4, ex4);
    STEPF(RL(tmv, 5), ec5, ex5);
    STEPF(RL(tmv, 6), ec6, ex6);
    STEPF(RL(tmv, 7), ec7, ex7);
  }

  // ---- tail: t = 1017..1023 (7 steps) ----
  {
    int tt = 1017 + (lane & 7);
    if (tt > 1023) tt = 1023;
    int tmv = tmeta[tt];
    float ex0 = exp2f(epf0 * LOG2E), ex1 = exp2f(epf1 * LOG2E);
    float ex2 = exp2f(epf2 * LOG2E), ex3 = exp2f(epf3 * LOG2E);
    float ex4 = exp2f(epf4 * LOG2E), ex5 = exp2f(epf5 * LOG2E);
    float ex6 = exp2f(epf6 * LOG2E);

    STEPF(RL(tmv, 0), epf0, ex0);
    STEPF(RL(tmv, 1), epf1, ex1);
    STEPF(RL(tmv, 2), epf2, ex2);
    STEPF(RL(tmv, 3), epf3, ex3);
    STEPF(RL(tmv, 4), epf4, ex4);
    STEPF(RL(tmv, 5), epf5, ex5);
    STEPF(RL(tmv, 6), epf6, ex6);
  }

  // ---- norm = Mk*ln2 + ln(sum_j A[j]); out = norm - gold ----
  float ssum = Aprev;
  float gsum = gtr;
  #pragma unroll
  for (int k = 32; k >= 1; k >>= 1) {
    ssum += __shfl_xor(ssum, k, 64);
    gsum += __shfl_xor(gsum, k, 64);
  }
  double norm = ((double)Mk + (double)log2f(ssum)) * 0.6931471805599453;
  double goldall = (double)gold + (double)gsum;
  if (lane == 0) out[b] = (float)(norm - goldall);
}

extern "C" void kernel_launch(void* const* d_in, const int* in_sizes, int n_in,
                              void* d_out, int out_size, void* d_ws, size_t ws_size,
                              hipStream_t stream) {
  const float* feats = (const float*)d_in[0];
  const int* tags = (const int*)d_in[1];
  const int* mask = (const int*)d_in[2];
  const float* trans = (const float*)d_in[3];
  float* out = (float*)d_out;

  int Bn = in_sizes[0] / (S_ * T_);  // 512
  hipLaunchKernelGGL(crf_scan, dim3(Bn), dim3(64), 0, stream,
                     feats, tags, mask, trans, out);
}